// Round 19
// baseline (185.030 us; speedup 1.0000x reference)
//
#include <hip/hip_runtime.h>
#include <hip/hip_bf16.h>

// Problem dims
#define NB 32
#define NT 64
#define NJ 22
#define ND 512
#define NH 8
#define NC 128
#define NDH 64
#define NR 1408   // T*N rows per (b)

typedef __attribute__((ext_vector_type(8))) short s16x8;   // 8 bf16 (4 VGPRs)
typedef __attribute__((ext_vector_type(4))) float fx4;     // MFMA accumulator

static __device__ __forceinline__ unsigned short f2bf(float f) {
    unsigned u = __builtin_bit_cast(unsigned, f);
    u += 0x7fffu + ((u >> 16) & 1u);   // RNE
    return (unsigned short)(u >> 16);
}

static __device__ __forceinline__ fx4 mfma16(s16x8 a, s16x8 b, fx4 c) {
    return __builtin_amdgcn_mfma_f32_16x16x32_bf16(a, b, c, 0, 0, 0);
}

// async global->LDS, 16B per lane. LDS dest is wave-uniform base; HW adds lane*16.
static __device__ __forceinline__ void gload16(const void* g, void* l) {
    __builtin_amdgcn_global_load_lds(
        (const __attribute__((address_space(1))) void*)g,
        (__attribute__((address_space(3))) void*)l,
        16, 0, 0);
}

// DPP row_ror:<N> over the 16-lane row (reduction step, no LDS traffic)
template <int CTRL>
static __device__ __forceinline__ float ror16(float v) {
    return __builtin_bit_cast(float,
        __builtin_amdgcn_update_dpp(0, __builtin_bit_cast(int, v),
                                    CTRL, 0xf, 0xf, true));
}

// ---------------------------------------------------------------------------
// Activation convert body (R16 form — conv is CLOSED after 6 null attempts).
// key = (flat_row/DIV) & 7 baked chunk-XOR swizzle.
template <int DIV>
static __device__ __forceinline__ void conv_act(
    const float* __restrict__ src, unsigned short* __restrict__ dst,
    long base, int tid)
{
    float4 L[8][2];
    #pragma unroll
    for (int g = 0; g < 8; ++g) {
        const float* p = src + base + g*2048 + tid*8;
        L[g][0] = *reinterpret_cast<const float4*>(p);
        L[g][1] = *reinterpret_cast<const float4*>(p + 4);
    }
    __builtin_amdgcn_sched_barrier(0);
    #pragma unroll
    for (int g = 0; g < 8; ++g) {
        const long i = base + g*2048 + tid*8;
        const int key = (int)(((unsigned)(i >> 9) / (unsigned)DIV) & 7u);
        const int c = (int)((i >> 3) & 7);
        const long jj = (i & ~63L) | ((long)(c ^ key) << 3);
        unsigned short t[8];
        t[0]=f2bf(L[g][0].x); t[1]=f2bf(L[g][0].y);
        t[2]=f2bf(L[g][0].z); t[3]=f2bf(L[g][0].w);
        t[4]=f2bf(L[g][1].x); t[5]=f2bf(L[g][1].y);
        t[6]=f2bf(L[g][1].z); t[7]=f2bf(L[g][1].w);
        *reinterpret_cast<s16x8*>(dst + jj) = *reinterpret_cast<s16x8*>(t);
    }
}

// ---------------------------------------------------------------------------
// ONE launch for all preprocessing.
// Blocks [0,1600):      weight transpose-convert, 25 matrices x (8x8) tiles.
//   Wt[n][k] = bf16 W[k][n], chunk-XOR swizzle on k (chunk ^ (n&7)).
// Blocks [1600,1728):   ctx f32->bf16, key = flat_row & 7.
// Blocks [1728,3136):   x   f32->bf16, key = (flat_row/22) & 7.
__global__ __launch_bounds__(256) void conv_all_k(
    const float* __restrict__ x, const float* __restrict__ ctx,
    const float* __restrict__ Wq, const float* __restrict__ Wk,
    const float* __restrict__ Wv, const float* __restrict__ Wout,
    unsigned short* __restrict__ xbf, unsigned short* __restrict__ cbf,
    unsigned short* __restrict__ WqT, unsigned short* __restrict__ WkT,
    unsigned short* __restrict__ WvT, unsigned short* __restrict__ WoutT)
{
    __shared__ float T[64][65];
    const long bid = blockIdx.x;
    const int tid = threadIdx.x;

    if (bid < 1600) {
        const int z = (int)(bid >> 6);
        const int rem = (int)(bid & 63);
        const int tbx = rem >> 3, tby = rem & 7;
        const float* W; unsigned short* Wt;
        if (z < 22)       { W = Wq + (long)z * 262144; Wt = WqT + (long)z * 262144; }
        else if (z == 22) { W = Wk;   Wt = WkT; }
        else if (z == 23) { W = Wv;   Wt = WvT; }
        else              { W = Wout; Wt = WoutT; }
        W  += (long)tbx * 64 * 512 + tby * 64;
        Wt += (long)tby * 64 * 512 + tbx * 64;
        const int r = tid >> 2, c0 = (tid & 3) * 16;
        #pragma unroll
        for (int i = 0; i < 4; ++i) {
            const float4 p = *reinterpret_cast<const float4*>(W + (long)r * 512 + c0 + i*4);
            T[r][c0 + i*4 + 0] = p.x; T[r][c0 + i*4 + 1] = p.y;
            T[r][c0 + i*4 + 2] = p.z; T[r][c0 + i*4 + 3] = p.w;
        }
        __syncthreads();
        unsigned short o[16];
        #pragma unroll
        for (int i = 0; i < 16; ++i) o[i] = f2bf(T[c0 + i][r]);
        const int ch0 = ((c0 >> 3) ^ (r & 7));
        *reinterpret_cast<s16x8*>(Wt + (long)r * 512 + ch0*8)     = *reinterpret_cast<s16x8*>(o);
        *reinterpret_cast<s16x8*>(Wt + (long)r * 512 + (ch0^1)*8) = *reinterpret_cast<s16x8*>(o + 8);
        return;
    }

    if (bid < 1728) {
        conv_act<1>(ctx, cbf, (bid - 1600) * 16384L, tid);
    } else {
        conv_act<NJ>(x, xbf, (bid - 1728) * 16384L, tid);
    }
}

// ---------------------------------------------------------------------------
// 8-wave single-buffer GEMM body: 128x256 tile, BK=64, 512 threads.
// BN=256 halves the A re-read vs BN=128 (A is the large operand for Q-proj
// and out-proj). Per-wave output 64x64 (acc 4x4, 64 VGPRs — same as the
// 4-wave body). LDS 48KB: As[128][64] + Bs[256][64], linear (global_load_lds);
// ds_read applies the chunk-XOR (key = row&7 — all tile offsets are
// multiples of 8, so key == lr&7 on both A and B reads; 0 conflicts R7 PMC).
// KV: 0 = normal store, 1 = K-pack kt[b][h][c][dh^swz],
//     2 = V-pack vt[b][h][dh][c^swz].
template <typename TC, int KV>
static __device__ __forceinline__ void gemm_body8(
    const unsigned short* __restrict__ A, long lda,
    const unsigned short* __restrict__ Bt,
    const float* __restrict__ bias,
    TC* __restrict__ C, long ldc,
    int bx, int by, int tid,
    unsigned short* As, unsigned short* Bs)
{
    const int w = tid >> 6, lane = tid & 63;
    const int srow = lane >> 3;            // 0..7
    const int scol = (lane & 7) * 8;
    // A: wave w stages rows w*16 + it*8 + srow (it=0..1)
    const unsigned short* Ag = A  + (long)(w*16 + srow) * lda + scol;
    // B: wave w stages rows w*32 + it*8 + srow (it=0..3)
    const unsigned short* Bg = Bt + (long)(w*32 + srow) * 512 + scol;

    const int lr = lane & 15, lk = lane >> 4;
    const int wm = w >> 2, wn = w & 3;     // 2 x 4 wave grid

    fx4 acc[4][4] = {};

    #pragma unroll
    for (int t = 0; t < 8; ++t) {
        const int kt = t * 64;
        char* Al = (char*)As + w * 2048;   // 2 x 1KB issues
        char* Bl = (char*)Bs + w * 4096;   // 4 x 1KB issues
        #pragma unroll
        for (int it = 0; it < 2; ++it)
            gload16(Ag + (long)it * 8 * lda + kt, Al + it * 1024);
        #pragma unroll
        for (int it = 0; it < 4; ++it)
            gload16(Bg + (long)it * 8 * 512 + kt, Bl + it * 1024);
        __syncthreads();        // drains vmcnt: tile in LDS
        #pragma unroll
        for (int ks = 0; ks < 2; ++ks) {
            const int cha = (ks*4 + lk) ^ (lr & 7);
            s16x8 a[4], b[4];
            #pragma unroll
            for (int m = 0; m < 4; ++m)
                a[m] = *reinterpret_cast<const s16x8*>(&As[(wm*64 + m*16 + lr)*64 + cha*8]);
            #pragma unroll
            for (int n = 0; n < 4; ++n)
                b[n] = *reinterpret_cast<const s16x8*>(&Bs[(wn*64 + n*16 + lr)*64 + cha*8]);
            #pragma unroll
            for (int m = 0; m < 4; ++m)
                #pragma unroll
                for (int n = 0; n < 4; ++n)
                    acc[m][n] = mfma16(a[m], b[n], acc[m][n]);
        }
        if (t < 7) __syncthreads();  // reads done before next STAGE
    }

    // epilogue: C/D layout col=lane&15, row=(lane>>4)*4+r
    #pragma unroll
    for (int n = 0; n < 4; ++n) {
        const int col = wn*64 + n*16 + lr;         // 0..255
        const float bv = bias[col];
        #pragma unroll
        for (int m = 0; m < 4; ++m) {
            #pragma unroll
            for (int r = 0; r < 4; ++r) {
                const int row = wm*64 + m*16 + lk*4 + r;   // 0..127
                const float val = acc[m][n][r] + bv;
                if constexpr (KV == 0) {
                    if constexpr (sizeof(TC) == 2)
                        reinterpret_cast<unsigned short*>(C)[(long)row*ldc + col] = f2bf(val);
                    else
                        reinterpret_cast<float*>(C)[(long)row*ldc + col] = val;
                } else {
                    const int grow = bx*128 + row;         // (b, c)
                    const int gcol = by*256 + col;         // (h, dh)
                    const int b = grow >> 7, c = grow & 127;
                    const int hh = gcol >> 6, dh = gcol & 63;
                    unsigned short* Cp = reinterpret_cast<unsigned short*>(C);
                    if constexpr (KV == 1) {
                        const int dhs = (dh & 7) | ((((dh >> 3) ^ (c & 7)) & 7) << 3);
                        Cp[(((long)b*8 + hh)*128 + c)*64 + dhs] = f2bf(val);
                    } else {
                        const int cs = (c & 7) | ((((c >> 3) ^ (dh & 7)) & 15) << 3);
                        Cp[(((long)b*8 + hh)*64 + dh)*128 + cs] = f2bf(val);
                    }
                }
            }
        }
    }
}

// ---------------------------------------------------------------------------
// Merged Q + K + V projection, ONE launch (832 blocks x 512 threads).
// Blocks [0,128):   KV-proj. lin>>6: 0=K, 1=V; rem: bx(32) x by(2).
// Blocks [128,832): Q-proj, 32 blocks per joint (16 row x 2 col tiles).
__global__ __launch_bounds__(512) void proj_all_k(
    const unsigned short* __restrict__ xbf,
    const unsigned short* __restrict__ cbf,
    const unsigned short* __restrict__ WqT,
    const unsigned short* __restrict__ WkT,
    const unsigned short* __restrict__ WvT,
    const float* __restrict__ bq, const float* __restrict__ bk,
    const float* __restrict__ bv,
    unsigned short* __restrict__ qbf,
    unsigned short* __restrict__ ktp,
    unsigned short* __restrict__ vtp)
{
    __shared__ unsigned short As[128*64];
    __shared__ unsigned short Bs[256*64];
    const int tid = threadIdx.x;
    const int bid = blockIdx.x;

    if (bid < 128) {
        // ---- KV projection ----
        int lin = bid;
        lin = (lin & 7) * 16 + (lin >> 3);         // XCD swizzle (nwg=128)
        const int sel = lin >> 6;                  // 0 = K, 1 = V
        const int rem = lin & 63;
        const int bx = rem & 31;                   // 32 row-tiles
        const int by = rem >> 5;                   // 2 col-tiles
        if (sel == 0) {
            gemm_body8<unsigned short, 1>(
                cbf + (long)bx * 128 * 512, 512,
                WkT + (long)by * 256 * 512, bk + by * 256,
                ktp, 0, bx, by, tid, As, Bs);
        } else {
            gemm_body8<unsigned short, 2>(
                cbf + (long)bx * 128 * 512, 512,
                WvT + (long)by * 256 * 512, bv + by * 256,
                vtp, 0, bx, by, tid, As, Bs);
        }
        return;
    }

    // ---- Q projection (per joint) ----
    const int r = bid - 128;
    const int j = r >> 5;                          // joint (32 blocks each)
    int lin = r & 31;
    lin = (lin & 7) * 4 + (lin >> 3);              // XCD swizzle (nwg=32)
    const int bx = lin & 15;                       // 16 row-tiles
    const int by = lin >> 4;                       // 2 col-tiles
    const long lda = (long)NJ * ND;
    gemm_body8<unsigned short, 0>(
        xbf + (long)bx * 128 * lda + (long)j * ND, lda,
        WqT + (long)j * 512 * 512 + (long)by * 256 * 512,
        bq + j * ND + by * 256,
        qbf + (long)bx * 128 * lda + (long)j * ND + by * 256, lda,
        bx, by, tid, As, Bs);
}

// ---------------------------------------------------------------------------
// Output projection: 128x256 tile, 512 threads, f32 output. Grid 352 x 2.
__global__ __launch_bounds__(512) void gemm_out_k(
    const unsigned short* __restrict__ A,     // obf, swizzled bf16
    const unsigned short* __restrict__ Bt,    // WoutT
    const float* __restrict__ bias,
    float* __restrict__ C)
{
    __shared__ unsigned short As[128*64];
    __shared__ unsigned short Bs[256*64];
    const int tid = threadIdx.x;

    const int nx = gridDim.x;                      // 352
    const int nwg = nx * gridDim.y;                // 704
    int lin = blockIdx.y * nx + blockIdx.x;
    lin = (lin & 7) * (nwg >> 3) + (lin >> 3);     // XCD swizzle (704%8==0)
    const int bx = lin % nx, by = lin / nx;

    gemm_body8<float, 0>(
        A + (long)bx * 128 * 512, 512,
        Bt + (long)by * 256 * 512, bias + by * 256,
        C + (long)bx * 128 * 512 + by * 256, 512,
        bx, by, tid, As, Bs);
}

// ---------------------------------------------------------------------------
// Attention v4 (unchanged): 2 q-tiles per block, Q in registers, K/V staged
// once, one barrier. Softmax via DPP row_ror. LDS 48KB -> 3 blocks/CU.
__global__ __launch_bounds__(256, 3) void attn4_k(
    const unsigned short* __restrict__ q,   // bf16 [B, NR, 512] linear
    const unsigned short* __restrict__ kt,  // bf16 [B,H,128,64] swizzled
    const unsigned short* __restrict__ vt,  // bf16 [B,H,64,128] swizzled
    unsigned short* __restrict__ o)         // bf16 [B, NR, 512] GEMM-swizzled
{
    __shared__ __align__(16) unsigned short Ks[128*64];
    __shared__ __align__(16) unsigned short Vs[64*128];
    __shared__ __align__(16) unsigned short Ps[64*128];

    const int tid = threadIdx.x;
    const int w = tid >> 6, lane = tid & 63;
    const int lr = lane & 15, lk = lane >> 4;
    const int r0 = blockIdx.x * 128;
    const int h = blockIdx.y;
    const int b = blockIdx.z;

    const unsigned short* kg = kt + ((long)(b*8+h))*8192 + w*2048 + lane*8;
    const unsigned short* vg = vt + ((long)(b*8+h))*8192 + w*2048 + lane*8;
    #pragma unroll
    for (int it = 0; it < 4; ++it) {
        gload16(kg + it*512, (char*)Ks + w*4096 + it*1024);
        gload16(vg + it*512, (char*)Vs + w*4096 + it*1024);
    }

    s16x8 qr[2][2];
    #pragma unroll
    for (int t = 0; t < 2; ++t) {
        const unsigned short* qb = q + ((long)b*NR + r0 + t*64 + w*16 + lr)*512 + h*64;
        #pragma unroll
        for (int kk = 0; kk < 2; ++kk)
            qr[t][kk] = *reinterpret_cast<const s16x8*>(qb + kk*32 + lk*8);
    }
    __syncthreads();

    const float SC = 0.125f * 1.44269504088896340736f;

    #pragma unroll
    for (int t = 0; t < 2; ++t) {
        fx4 s[8] = {};
        __builtin_amdgcn_s_setprio(1);
        #pragma unroll
        for (int kk = 0; kk < 2; ++kk) {
            #pragma unroll
            for (int f = 0; f < 8; ++f) {
                const int c = f*16 + lr;
                const int chunk = (kk*4 + lk) ^ (c & 7);
                s16x8 bk = *reinterpret_cast<const s16x8*>(&Ks[c*64 + chunk*8]);
                s[f] = mfma16(qr[t][kk], bk, s[f]);
            }
        }
        __builtin_amdgcn_s_setprio(0);

        #pragma unroll
        for (int rr = 0; rr < 4; ++rr) {
            const int row = w*16 + lk*4 + rr;
            float mx = fmaxf(fmaxf(fmaxf(s[0][rr], s[1][rr]), fmaxf(s[2][rr], s[3][rr])),
                             fmaxf(fmaxf(s[4][rr], s[5][rr]), fmaxf(s[6][rr], s[7][rr])));
            mx = fmaxf(mx, ror16<0x128>(mx));
            mx = fmaxf(mx, ror16<0x124>(mx));
            mx = fmaxf(mx, ror16<0x122>(mx));
            mx = fmaxf(mx, ror16<0x121>(mx));
            float p[8]; float sum = 0.f;
            #pragma unroll
            for (int f = 0; f < 8; ++f) {
                p[f] = exp2f((s[f][rr] - mx) * SC);
                sum += p[f];
            }
            sum += ror16<0x128>(sum);
            sum += ror16<0x124>(sum);
            sum += ror16<0x122>(sum);
            sum += ror16<0x121>(sum);
            const float inv = 1.0f / sum;
            #pragma unroll
            for (int f = 0; f < 8; ++f) {
                const int cg = f*16 + lr;
                Ps[row*128 + (((cg >> 3) ^ (row & 7)) << 3) + (cg & 7)] = f2bf(p[f] * inv);
            }
        }

        fx4 oacc[4] = {};
        __builtin_amdgcn_s_setprio(1);
        #pragma unroll
        for (int kt4 = 0; kt4 < 4; ++kt4) {
            const int prow = w*16 + lr;
            s16x8 ap = *reinterpret_cast<const s16x8*>(
                &Ps[prow*128 + (((kt4*4 + lk) ^ (prow & 7)) << 3)]);
            #pragma unroll
            for (int bn = 0; bn < 4; ++bn) {
                const int dh = bn*16 + lr;
                const int chunk = (kt4*4 + lk) ^ (dh & 7);
                s16x8 bv = *reinterpret_cast<const s16x8*>(&Vs[dh*128 + chunk*8]);
                oacc[bn] = mfma16(ap, bv, oacc[bn]);
            }
        }
        __builtin_amdgcn_s_setprio(0);

        unsigned short* ob = o + ((long)b*NR + r0 + t*64)*512 + h*64;
        #pragma unroll
        for (int bn = 0; bn < 4; ++bn)
            #pragma unroll
            for (int rr = 0; rr < 4; ++rr) {
                const int row = w*16 + lk*4 + rr;
                const int colg = bn*16 + lr;
                const int ch = ((colg >> 3) ^ (row & 7));
                ob[(long)row*512 + ch*8 + (lr & 7)] = f2bf(oacc[bn][rr]);
            }
    }
}

extern "C" void kernel_launch(void* const* d_in, const int* in_sizes, int n_in,
                              void* d_out, int out_size, void* d_ws, size_t ws_size,
                              hipStream_t stream)
{
    const float* x    = (const float*)d_in[0];
    const float* ctx  = (const float*)d_in[1];
    const float* Wq   = (const float*)d_in[2];
    const float* bq   = (const float*)d_in[3];
    const float* Wk   = (const float*)d_in[4];
    const float* bk   = (const float*)d_in[5];
    const float* Wv   = (const float*)d_in[6];
    const float* bv   = (const float*)d_in[7];
    const float* Wout = (const float*)d_in[8];
    const float* bout = (const float*)d_in[9];
    float* out = (float*)d_out;

    const size_t NX  = (size_t)45056 * 512;   // x / q / o elements
    const size_t NKV = (size_t)4096 * 512;    // ctx / k / v elements
    const size_t NW  = (size_t)512 * 512;     // one weight matrix

    unsigned short* xbf   = (unsigned short*)d_ws;     // also obf (both GEMM-swizzled)
    unsigned short* qbf   = xbf   + NX;                // linear
    unsigned short* cbf   = qbf   + NX;                // ctx bf16, GEMM-swizzled
    unsigned short* ktp   = cbf   + NKV;               // packed swizzled K
    unsigned short* vtp   = ktp   + NKV;               // packed swizzled V^T
    unsigned short* WqT   = vtp   + NKV;               // 22 matrices, [n][k] swizzled
    unsigned short* WkT   = WqT   + 22 * NW;
    unsigned short* WvT   = WkT   + NW;
    unsigned short* WoutT = WvT   + NW;
    unsigned short* obf   = xbf;

    // 1) ALL preprocessing in one launch (weights, then ctx, then x)
    conv_all_k<<<dim3(3136), 256, 0, stream>>>(
        x, ctx, Wq, Wk, Wv, Wout, xbf, cbf, WqT, WkT, WvT, WoutT);

    // 2) merged Q + K + V projections, 512-thread 128x256-tile blocks
    proj_all_k<<<dim3(832), 512, 0, stream>>>(
        xbf, cbf, WqT, WkT, WvT, bq, bk, bv, qbf, ktp, vtp);

    // 3) fused attention: one block per (128-row q-pair, h, b)
    attn4_k<<<dim3(NR/128, NH, NB), 256, 0, stream>>>(qbf, ktp, vtp, obf);

    // 4) output projection: 128x256 tiles, f32 output
    gemm_out_k<<<dim3(352, 2, 1), 512, 0, stream>>>(obf, WoutT, bout, out);
}

// Round 20
// 175.850 us; speedup vs baseline: 1.0522x; 1.0522x over previous
//
#include <hip/hip_runtime.h>
#include <hip/hip_bf16.h>

// Problem dims
#define NB 32
#define NT 64
#define NJ 22
#define ND 512
#define NH 8
#define NC 128
#define NDH 64
#define NR 1408   // T*N rows per (b)

typedef __attribute__((ext_vector_type(8))) short s16x8;   // 8 bf16 (4 VGPRs)
typedef __attribute__((ext_vector_type(4))) float fx4;     // MFMA accumulator

static __device__ __forceinline__ unsigned short f2bf(float f) {
    unsigned u = __builtin_bit_cast(unsigned, f);
    u += 0x7fffu + ((u >> 16) & 1u);   // RNE
    return (unsigned short)(u >> 16);
}

static __device__ __forceinline__ fx4 mfma16(s16x8 a, s16x8 b, fx4 c) {
    return __builtin_amdgcn_mfma_f32_16x16x32_bf16(a, b, c, 0, 0, 0);
}

// async global->LDS, 16B per lane. LDS dest is wave-uniform base; HW adds lane*16.
static __device__ __forceinline__ void gload16(const void* g, void* l) {
    __builtin_amdgcn_global_load_lds(
        (const __attribute__((address_space(1))) void*)g,
        (__attribute__((address_space(3))) void*)l,
        16, 0, 0);
}

// DPP row_ror:<N> over the 16-lane row (reduction step, no LDS traffic)
template <int CTRL>
static __device__ __forceinline__ float ror16(float v) {
    return __builtin_bit_cast(float,
        __builtin_amdgcn_update_dpp(0, __builtin_bit_cast(int, v),
                                    CTRL, 0xf, 0xf, true));
}

// ---------------------------------------------------------------------------
// Activation convert body: 8 coalesced slabs/block (32B/lane/load);
// sched_barrier(0) between load batch and convert/store loop.
// key = (flat_row/DIV) & 7 baked chunk-XOR swizzle.
template <int DIV>
static __device__ __forceinline__ void conv_act(
    const float* __restrict__ src, unsigned short* __restrict__ dst,
    long base, int tid)
{
    float4 L[8][2];
    #pragma unroll
    for (int g = 0; g < 8; ++g) {
        const float* p = src + base + g*2048 + tid*8;
        L[g][0] = *reinterpret_cast<const float4*>(p);
        L[g][1] = *reinterpret_cast<const float4*>(p + 4);
    }
    __builtin_amdgcn_sched_barrier(0);   // all 16 loads issued before any use
    #pragma unroll
    for (int g = 0; g < 8; ++g) {
        const long i = base + g*2048 + tid*8;
        const int key = (int)(((unsigned)(i >> 9) / (unsigned)DIV) & 7u);
        const int c = (int)((i >> 3) & 7);
        const long jj = (i & ~63L) | ((long)(c ^ key) << 3);
        unsigned short t[8];
        t[0]=f2bf(L[g][0].x); t[1]=f2bf(L[g][0].y);
        t[2]=f2bf(L[g][0].z); t[3]=f2bf(L[g][0].w);
        t[4]=f2bf(L[g][1].x); t[5]=f2bf(L[g][1].y);
        t[6]=f2bf(L[g][1].z); t[7]=f2bf(L[g][1].w);
        *reinterpret_cast<s16x8*>(dst + jj) = *reinterpret_cast<s16x8*>(t);
    }
}

// ---------------------------------------------------------------------------
// ONE launch for all preprocessing.
// Blocks [0,1600):      weight transpose-convert, 25 matrices x (8x8) tiles.
//   Wt[n][k] = bf16 W[k][n], chunk-XOR swizzle on k (chunk ^ (n&7)).
// Blocks [1600,1728):   ctx f32->bf16, key = flat_row & 7.
// Blocks [1728,3136):   x   f32->bf16, key = (flat_row/22) & 7
//   (matches the Q-proj's lda=NJ*512 tile rows).
__global__ __launch_bounds__(256) void conv_all_k(
    const float* __restrict__ x, const float* __restrict__ ctx,
    const float* __restrict__ Wq, const float* __restrict__ Wk,
    const float* __restrict__ Wv, const float* __restrict__ Wout,
    unsigned short* __restrict__ xbf, unsigned short* __restrict__ cbf,
    unsigned short* __restrict__ WqT, unsigned short* __restrict__ WkT,
    unsigned short* __restrict__ WvT, unsigned short* __restrict__ WoutT)
{
    __shared__ float T[64][65];
    const long bid = blockIdx.x;
    const int tid = threadIdx.x;

    if (bid < 1600) {
        // ---- weight transpose-convert ----
        const int z = (int)(bid >> 6);
        const int rem = (int)(bid & 63);
        const int tbx = rem >> 3, tby = rem & 7;
        const float* W; unsigned short* Wt;
        if (z < 22)       { W = Wq + (long)z * 262144; Wt = WqT + (long)z * 262144; }
        else if (z == 22) { W = Wk;   Wt = WkT; }
        else if (z == 23) { W = Wv;   Wt = WvT; }
        else              { W = Wout; Wt = WoutT; }
        W  += (long)tbx * 64 * 512 + tby * 64;
        Wt += (long)tby * 64 * 512 + tbx * 64;
        const int r = tid >> 2, c0 = (tid & 3) * 16;
        #pragma unroll
        for (int i = 0; i < 4; ++i) {
            const float4 p = *reinterpret_cast<const float4*>(W + (long)r * 512 + c0 + i*4);
            T[r][c0 + i*4 + 0] = p.x; T[r][c0 + i*4 + 1] = p.y;
            T[r][c0 + i*4 + 2] = p.z; T[r][c0 + i*4 + 3] = p.w;
        }
        __syncthreads();
        unsigned short o[16];
        #pragma unroll
        for (int i = 0; i < 16; ++i) o[i] = f2bf(T[c0 + i][r]);
        const int ch0 = ((c0 >> 3) ^ (r & 7));   // c0>>3 even; second chunk = ch0^1
        *reinterpret_cast<s16x8*>(Wt + (long)r * 512 + ch0*8)     = *reinterpret_cast<s16x8*>(o);
        *reinterpret_cast<s16x8*>(Wt + (long)r * 512 + (ch0^1)*8) = *reinterpret_cast<s16x8*>(o + 8);
        return;
    }

    // ---- activation converts (zero LDS traffic; T unused on this path) ----
    if (bid < 1728) {
        conv_act<1>(ctx, cbf, (bid - 1600) * 16384L, tid);
    } else {
        conv_act<NJ>(x, xbf, (bid - 1728) * 16384L, tid);
    }
}

// ---------------------------------------------------------------------------
// Shared single-buffer GEMM body (m97 structure, 128x128 tile, BK=64,
// 4 waves). A/Bt chunk-XOR swizzled in global; LDS linear; ds_read applies
// the XOR -> conflict-free (0 conflicts, R7 PMC). KV: 0 = normal store,
// 1 = K-pack kt[b][h][c][dh^swz], 2 = V-pack vt[b][h][dh][c^swz].
template <typename TC, int KV>
static __device__ __forceinline__ void gemm_body(
    const unsigned short* __restrict__ A, long lda,
    const unsigned short* __restrict__ Bt,
    const float* __restrict__ bias,
    TC* __restrict__ C, long ldc,
    int bx, int by, int tid,
    unsigned short* As, unsigned short* Bs)
{
    const int w = tid >> 6, lane = tid & 63;
    const int srow = lane >> 3;
    const int scol = (lane & 7) * 8;
    const unsigned short* Ag = A  + (long)(w*8 + srow) * lda + scol;
    const unsigned short* Bg = Bt + (long)(w*8 + srow) * 512 + scol;

    const int lr = lane & 15, lk = lane >> 4;
    const int wm = w >> 1, wn = w & 1;

    fx4 acc[4][4] = {};

    #pragma unroll
    for (int t = 0; t < 8; ++t) {
        const int kt = t * 64;
        char* Al = (char*)As + w * 1024;
        char* Bl = (char*)Bs + w * 1024;
        #pragma unroll
        for (int it = 0; it < 4; ++it)
            gload16(Ag + (long)it * 32 * lda + kt, Al + it * 4096);
        #pragma unroll
        for (int it = 0; it < 4; ++it)
            gload16(Bg + (long)it * 32 * 512 + kt, Bl + it * 4096);
        __syncthreads();        // drains vmcnt: tile in LDS
        #pragma unroll
        for (int ks = 0; ks < 2; ++ks) {
            const int cha = (ks*4 + lk) ^ (lr & 7);
            s16x8 a[4], b[4];
            #pragma unroll
            for (int m = 0; m < 4; ++m)
                a[m] = *reinterpret_cast<const s16x8*>(&As[(wm*64 + m*16 + lr)*64 + cha*8]);
            #pragma unroll
            for (int n = 0; n < 4; ++n)
                b[n] = *reinterpret_cast<const s16x8*>(&Bs[(wn*64 + n*16 + lr)*64 + cha*8]);
            #pragma unroll
            for (int m = 0; m < 4; ++m)
                #pragma unroll
                for (int n = 0; n < 4; ++n)
                    acc[m][n] = mfma16(a[m], b[n], acc[m][n]);
        }
        if (t < 7) __syncthreads();  // reads done before next STAGE
    }

    // epilogue: C/D layout col=lane&15, row=(lane>>4)*4+r
    #pragma unroll
    for (int n = 0; n < 4; ++n) {
        const int col = wn*64 + n*16 + lr;
        const float bv = bias[col];
        #pragma unroll
        for (int m = 0; m < 4; ++m) {
            #pragma unroll
            for (int r = 0; r < 4; ++r) {
                const int row = wm*64 + m*16 + lk*4 + r;
                const float val = acc[m][n][r] + bv;
                if constexpr (KV == 0) {
                    if constexpr (sizeof(TC) == 2)
                        reinterpret_cast<unsigned short*>(C)[(long)row*ldc + col] = f2bf(val);
                    else
                        reinterpret_cast<float*>(C)[(long)row*ldc + col] = val;
                } else {
                    const int grow = bx*128 + row;       // (b, c)
                    const int gcol = by*128 + col;       // (h, dh)
                    const int b = grow >> 7, c = grow & 127;
                    const int hh = gcol >> 6, dh = gcol & 63;
                    unsigned short* Cp = reinterpret_cast<unsigned short*>(C);
                    if constexpr (KV == 1) {
                        const int dhs = (dh & 7) | ((((dh >> 3) ^ (c & 7)) & 7) << 3);
                        Cp[(((long)b*8 + hh)*128 + c)*64 + dhs] = f2bf(val);
                    } else {
                        const int cs = (c & 7) | ((((c >> 3) ^ (dh & 7)) & 15) << 3);
                        Cp[(((long)b*8 + hh)*64 + dh)*128 + cs] = f2bf(val);
                    }
                }
            }
        }
    }
}

// ---------------------------------------------------------------------------
// Merged Q + K + V projection, ONE launch (1664 blocks).
// Blocks [0,256):    KV-proj (M=4096 ctx rows). lin 0-127 -> K-pack (by 0-3),
//                    lin 128-255 -> V-pack. Placed FIRST so these 256 blocks
//                    co-schedule with Q-proj (R16: +7.5us total).
// Blocks [256,1664): Q-proj per joint j = (bid-256)/64, 16x4 sub-grid.
__global__ __launch_bounds__(256) void proj_all_k(
    const unsigned short* __restrict__ xbf,   // swizzled bf16 x
    const unsigned short* __restrict__ cbf,   // swizzled bf16 ctx
    const unsigned short* __restrict__ WqT,
    const unsigned short* __restrict__ WkT,
    const unsigned short* __restrict__ WvT,
    const float* __restrict__ bq, const float* __restrict__ bk,
    const float* __restrict__ bv,
    unsigned short* __restrict__ qbf,
    unsigned short* __restrict__ ktp,
    unsigned short* __restrict__ vtp)
{
    __shared__ unsigned short As[128*64];
    __shared__ unsigned short Bs[128*64];
    const int tid = threadIdx.x;
    const int bid = blockIdx.x;

    if (bid < 256) {
        // ---- KV projection ----
        int lin = bid;
        lin = (lin & 7) * 32 + (lin >> 3);        // XCD swizzle (nwg=256)
        const int bx = lin & 31;                  // 32 row-tiles
        const int byq = lin >> 5;                 // 0..7
        if (byq < 4) {
            gemm_body<unsigned short, 1>(
                cbf + (long)bx * 128 * 512, 512,
                WkT + (long)byq * 128 * 512, bk + byq * 128,
                ktp, 0, bx, byq, tid, As, Bs);
        } else {
            const int byv = byq - 4;
            gemm_body<unsigned short, 2>(
                cbf + (long)bx * 128 * 512, 512,
                WvT + (long)byv * 128 * 512, bv + byv * 128,
                vtp, 0, bx, byv, tid, As, Bs);
        }
        return;
    }

    // ---- Q projection (per joint) ----
    const int r = bid - 256;
    const int j = r >> 6;                          // joint
    int lin = r & 63;
    lin = (lin & 7) * 8 + (lin >> 3);              // XCD swizzle (nwg=64)
    const int bx = lin & 15;                       // 16 row-tiles
    const int by = lin >> 4;                       // 4 col-tiles
    const long lda = (long)NJ * ND;
    gemm_body<unsigned short, 0>(
        xbf + (long)bx * 128 * lda + (long)j * ND, lda,
        WqT + (long)j * 512 * 512 + (long)by * 128 * 512,
        bq + j * ND + by * 128,
        qbf + (long)bx * 128 * lda + (long)j * ND + by * 128, lda,
        bx, by, tid, As, Bs);
}

// ---------------------------------------------------------------------------
// Output projection: 128x128 tile single-buffer GEMM, f32 output.
__global__ __launch_bounds__(256) void gemm_out_k(
    const unsigned short* __restrict__ A,     // obf, swizzled bf16
    const unsigned short* __restrict__ Bt,    // WoutT
    const float* __restrict__ bias,
    float* __restrict__ C)
{
    __shared__ unsigned short As[128*64];
    __shared__ unsigned short Bs[128*64];
    const int tid = threadIdx.x;

    const int nx = gridDim.x;                      // 352
    const int nwg = nx * gridDim.y;                // 1408
    int lin = blockIdx.y * nx + blockIdx.x;
    lin = (lin & 7) * (nwg >> 3) + (lin >> 3);     // XCD swizzle
    const int bx = lin % nx, by = lin / nx;

    gemm_body<float, 0>(
        A + (long)bx * 128 * 512, 512,
        Bt + (long)by * 128 * 512, bias + by * 128,
        C + (long)bx * 128 * 512 + by * 128, 512,
        bx, by, tid, As, Bs);
}

// ---------------------------------------------------------------------------
// Attention v4: 2 q-tiles (2x64 rows) per block, Q direct to registers (no
// Q LDS, no Q barrier), K/V staged once, dedicated P region -> ONE barrier
// per block. Softmax via DPP row_ror. LDS 48KB -> 3 blocks/CU.
__global__ __launch_bounds__(256, 3) void attn4_k(
    const unsigned short* __restrict__ q,   // bf16 [B, NR, 512] linear
    const unsigned short* __restrict__ kt,  // bf16 [B,H,128,64] swizzled
    const unsigned short* __restrict__ vt,  // bf16 [B,H,64,128] swizzled
    unsigned short* __restrict__ o)         // bf16 [B, NR, 512] GEMM-swizzled
{
    __shared__ __align__(16) unsigned short Ks[128*64];   // K [c][dh] swz
    __shared__ __align__(16) unsigned short Vs[64*128];   // V^T [dh][c] swz
    __shared__ __align__(16) unsigned short Ps[64*128];   // P [t][c] swz

    const int tid = threadIdx.x;
    const int w = tid >> 6, lane = tid & 63;
    const int lr = lane & 15, lk = lane >> 4;
    const int r0 = blockIdx.x * 128;        // 2 tiles of 64 rows
    const int h = blockIdx.y;
    const int b = blockIdx.z;

    // stage K/V (once for both q-tiles)
    const unsigned short* kg = kt + ((long)(b*8+h))*8192 + w*2048 + lane*8;
    const unsigned short* vg = vt + ((long)(b*8+h))*8192 + w*2048 + lane*8;
    #pragma unroll
    for (int it = 0; it < 4; ++it) {
        gload16(kg + it*512, (char*)Ks + w*4096 + it*1024);
        gload16(vg + it*512, (char*)Vs + w*4096 + it*1024);
    }

    // Q fragments for BOTH tiles -> registers
    s16x8 qr[2][2];
    #pragma unroll
    for (int t = 0; t < 2; ++t) {
        const unsigned short* qb = q + ((long)b*NR + r0 + t*64 + w*16 + lr)*512 + h*64;
        #pragma unroll
        for (int kk = 0; kk < 2; ++kk)
            qr[t][kk] = *reinterpret_cast<const s16x8*>(qb + kk*32 + lk*8);
    }
    __syncthreads();   // K/V in LDS (drains vmcnt)

    const float SC = 0.125f * 1.44269504088896340736f;   // scale * log2(e)

    #pragma unroll
    for (int t = 0; t < 2; ++t) {
        // ---- S = Q K^T (16 x 128 per wave) ----
        fx4 s[8] = {};
        __builtin_amdgcn_s_setprio(1);
        #pragma unroll
        for (int kk = 0; kk < 2; ++kk) {
            #pragma unroll
            for (int f = 0; f < 8; ++f) {
                const int c = f*16 + lr;
                const int chunk = (kk*4 + lk) ^ (c & 7);
                s16x8 bk = *reinterpret_cast<const s16x8*>(&Ks[c*64 + chunk*8]);
                s[f] = mfma16(qr[t][kk], bk, s[f]);
            }
        }
        __builtin_amdgcn_s_setprio(0);

        // ---- softmax: in-lane + DPP row_ror reductions over 16-lane rows ----
        #pragma unroll
        for (int rr = 0; rr < 4; ++rr) {
            const int row = w*16 + lk*4 + rr;
            float mx = fmaxf(fmaxf(fmaxf(s[0][rr], s[1][rr]), fmaxf(s[2][rr], s[3][rr])),
                             fmaxf(fmaxf(s[4][rr], s[5][rr]), fmaxf(s[6][rr], s[7][rr])));
            mx = fmaxf(mx, ror16<0x128>(mx));   // ror 8
            mx = fmaxf(mx, ror16<0x124>(mx));   // ror 4
            mx = fmaxf(mx, ror16<0x122>(mx));   // ror 2
            mx = fmaxf(mx, ror16<0x121>(mx));   // ror 1
            float p[8]; float sum = 0.f;
            #pragma unroll
            for (int f = 0; f < 8; ++f) {
                p[f] = exp2f((s[f][rr] - mx) * SC);
                sum += p[f];
            }
            sum += ror16<0x128>(sum);
            sum += ror16<0x124>(sum);
            sum += ror16<0x122>(sum);
            sum += ror16<0x121>(sum);
            const float inv = 1.0f / sum;
            #pragma unroll
            for (int f = 0; f < 8; ++f) {
                const int cg = f*16 + lr;
                Ps[row*128 + (((cg >> 3) ^ (row & 7)) << 3) + (cg & 7)] = f2bf(p[f] * inv);
            }
        }
        // no barrier: wave reads back only its own P rows

        // ---- O = P V (16 x 64 per wave, K = 128) ----
        fx4 oacc[4] = {};
        __builtin_amdgcn_s_setprio(1);
        #pragma unroll
        for (int kt4 = 0; kt4 < 4; ++kt4) {
            const int prow = w*16 + lr;
            s16x8 ap = *reinterpret_cast<const s16x8*>(
                &Ps[prow*128 + (((kt4*4 + lk) ^ (prow & 7)) << 3)]);
            #pragma unroll
            for (int bn = 0; bn < 4; ++bn) {
                const int dh = bn*16 + lr;
                const int chunk = (kt4*4 + lk) ^ (dh & 7);
                s16x8 bv = *reinterpret_cast<const s16x8*>(&Vs[dh*128 + chunk*8]);
                oacc[bn] = mfma16(ap, bv, oacc[bn]);
            }
        }
        __builtin_amdgcn_s_setprio(0);

        // ---- store O with GEMM chunk-XOR swizzle ----
        unsigned short* ob = o + ((long)b*NR + r0 + t*64)*512 + h*64;
        #pragma unroll
        for (int bn = 0; bn < 4; ++bn)
            #pragma unroll
            for (int rr = 0; rr < 4; ++rr) {
                const int row = w*16 + lk*4 + rr;
                const int colg = bn*16 + lr;
                const int ch = ((colg >> 3) ^ (row & 7));
                ob[(long)row*512 + ch*8 + (lr & 7)] = f2bf(oacc[bn][rr]);
            }
        // P region reused next tile by the same wave only -> no barrier
    }
}

extern "C" void kernel_launch(void* const* d_in, const int* in_sizes, int n_in,
                              void* d_out, int out_size, void* d_ws, size_t ws_size,
                              hipStream_t stream)
{
    const float* x    = (const float*)d_in[0];
    const float* ctx  = (const float*)d_in[1];
    const float* Wq   = (const float*)d_in[2];
    const float* bq   = (const float*)d_in[3];
    const float* Wk   = (const float*)d_in[4];
    const float* bk   = (const float*)d_in[5];
    const float* Wv   = (const float*)d_in[6];
    const float* bv   = (const float*)d_in[7];
    const float* Wout = (const float*)d_in[8];
    const float* bout = (const float*)d_in[9];
    float* out = (float*)d_out;

    const size_t NX  = (size_t)45056 * 512;   // x / q / o elements
    const size_t NKV = (size_t)4096 * 512;    // ctx / k / v elements
    const size_t NW  = (size_t)512 * 512;     // one weight matrix

    unsigned short* xbf   = (unsigned short*)d_ws;     // also obf (both GEMM-swizzled)
    unsigned short* qbf   = xbf   + NX;                // linear
    unsigned short* cbf   = qbf   + NX;                // ctx bf16, GEMM-swizzled
    unsigned short* ktp   = cbf   + NKV;               // packed swizzled K
    unsigned short* vtp   = ktp   + NKV;               // packed swizzled V^T
    unsigned short* WqT   = vtp   + NKV;               // 22 matrices, [n][k] swizzled
    unsigned short* WkT   = WqT   + 22 * NW;
    unsigned short* WvT   = WkT   + NW;
    unsigned short* WoutT = WvT   + NW;
    unsigned short* obf   = xbf;

    // 1) ALL preprocessing in one launch (weights, then ctx, then x)
    conv_all_k<<<dim3(3136), 256, 0, stream>>>(
        x, ctx, Wq, Wk, Wv, Wout, xbf, cbf, WqT, WkT, WvT, WoutT);

    // 2) merged Q + K + V projections in one launch (KV blocks first)
    proj_all_k<<<dim3(1664), 256, 0, stream>>>(
        xbf, cbf, WqT, WkT, WvT, bq, bk, bv, qbf, ktp, vtp);

    // 3) fused attention: one block per (128-row q-pair, h, b)
    attn4_k<<<dim3(NR/128, NH, NB), 256, 0, stream>>>(qbf, ktp, vtp, obf);

    // 4) output projection: bf16 A (pre-swizzled by attn4), f32 output
    gemm_out_k<<<dim3(352, 4, 1), 256, 0, stream>>>(obf, WoutT, bout, out);
}